// Round 9
// baseline (187.909 us; speedup 1.0000x reference)
//
#include <hip/hip_runtime.h>
#include <math.h>

#define N_ROWS 32768
#define K_CODES 8192
#define DIM 64
#define CHUNKS 4
#define CPC (K_CODES / CHUNKS)   // 2048 codes per chunk
#define TILES (CPC / 32)         // 64 tiles of 32 codes

using half8  = __attribute__((ext_vector_type(8))) _Float16;
using f32x16 = __attribute__((ext_vector_type(16))) float;

// ---------------- ws layout ----------------
#define WS_W2HL   0          // u32 w2hl[8192] (packed f16 hi/lo of w2)   32 KB
#define WS_COUNTS 32768      // int counts[8192]                          32 KB
#define WS_CSUM   65536      // float csum (+pad)                         16 B
#define WS_BEST   65552      // u64 best[32768]                           256 KB
#define WS_X2     327696     // float x2g[32768]                          128 KB
#define WS_WM2    458768     // _Float16 wm2hl[8192][128]  2 MB  (-2W: hi[64]|lo[64])

__device__ __forceinline__ void gload_lds16(const _Float16* g, _Float16* l) {
    __builtin_amdgcn_global_load_lds(
        (const __attribute__((address_space(1))) void*)g,
        (__attribute__((address_space(3))) void*)l, 16, 0, 0);
}

// ---------------- kernel 1: (-2W) split + w2 packed + x2 + init ----------------
__global__ __launch_bounds__(256) void vq_prep(const float* __restrict__ W,
                                               const float* __restrict__ x,
                                               _Float16* __restrict__ wm2hl,
                                               unsigned* __restrict__ w2hl,
                                               float* __restrict__ x2g,
                                               unsigned long long* __restrict__ best,
                                               int* __restrict__ counts,
                                               float* __restrict__ csum) {
    int g = blockIdx.x * 256 + threadIdx.x;   // 0 .. 524287
    int code = g >> 6, k = g & 63;
    float w = W[g];
    float wm2 = -2.0f * w;
    _Float16 h  = (_Float16)wm2;
    _Float16 lo = (_Float16)(wm2 - (float)h);
    wm2hl[(size_t)code * 128 + k]      = h;
    wm2hl[(size_t)code * 128 + 64 + k] = lo;
    float s = w * w;
    #pragma unroll
    for (int off = 32; off; off >>= 1) s += __shfl_down(s, off);
    if (k == 0) {
        _Float16 wh = (_Float16)s;
        _Float16 wl = (_Float16)(s - (float)wh);
        unsigned pk = (unsigned)(unsigned short)__builtin_bit_cast(unsigned short, wh)
                    | ((unsigned)(unsigned short)__builtin_bit_cast(unsigned short, wl) << 16);
        w2hl[code] = pk;
    }
    // x2: thread g owns x[4g..4g+3]; 16 lanes per row
    float4 xv = *(const float4*)(x + (size_t)g * 4);
    float ss = xv.x * xv.x + xv.y * xv.y + xv.z * xv.z + xv.w * xv.w;
    #pragma unroll
    for (int off = 8; off; off >>= 1) ss += __shfl_down(ss, off);
    if ((g & 15) == 0) x2g[g >> 4] = ss;
    if (g < N_ROWS)  best[g] = ~0ULL;
    if (g < K_CODES) counts[g] = 0;
    if (g == 0)      *csum = 0.f;
}

// ---------------- kernel 2: barrierless MFMA scores + per-row argmin ----------------
// 4 waves/block, each wave: 64 rows (2 groups of 32), PRIVATE 2x8KB LDS double
// buffer, per-wave counted vmcnt. No __syncthreads in the K-loop.
__global__ __launch_bounds__(256, 2) void vq_mfma(const float* __restrict__ x,
                                                  const _Float16* __restrict__ wm2hl,
                                                  const unsigned* __restrict__ w2g,
                                                  unsigned long long* __restrict__ best) {
    __shared__ __align__(16) _Float16 lds[4][2][4096];  // [wave][slot][8KB]
    __shared__ unsigned w2lds[CPC];                     // 8 KB

    const int t     = threadIdx.x;
    const int wv    = t >> 6;
    const int l     = t & 63;
    const int ln31  = l & 31;
    const int lhalf = l >> 5;
    const int chunk = blockIdx.x & (CHUNKS - 1);
    const int rblk  = blockIdx.x / CHUNKS;
    const int rowb  = rblk * 256 + wv * 64;    // wave owns 64 rows
    const int cbase = chunk * CPC;

    // stage w2 chunk (block-shared, written once before the single barrier)
    for (int i = t; i < CPC; i += 256) w2lds[i] = w2g[cbase + i];

    // A fragments: 2 row groups, exact f16 hi/lo split of x
    half8 ahi0[4], alo0[4], ahi1[4], alo1[4];
    {
        const float* xr0 = x + (size_t)(rowb + ln31) * DIM + lhalf * 8;
        const float* xr1 = x + (size_t)(rowb + 32 + ln31) * DIM + lhalf * 8;
        #pragma unroll
        for (int kt = 0; kt < 4; ++kt) {
            float4 a0 = *(const float4*)(xr0 + kt * 16);
            float4 a1 = *(const float4*)(xr0 + kt * 16 + 4);
            float4 b0 = *(const float4*)(xr1 + kt * 16);
            float4 b1 = *(const float4*)(xr1 + kt * 16 + 4);
            float fa[8] = {a0.x, a0.y, a0.z, a0.w, a1.x, a1.y, a1.z, a1.w};
            float fb[8] = {b0.x, b0.y, b0.z, b0.w, b1.x, b1.y, b1.z, b1.w};
            #pragma unroll
            for (int j = 0; j < 8; ++j) {
                _Float16 h0 = (_Float16)fa[j];
                _Float16 h1 = (_Float16)fb[j];
                ahi0[kt][j] = h0; alo0[kt][j] = (_Float16)(fa[j] - (float)h0);
                ahi1[kt][j] = h1; alo1[kt][j] = (_Float16)(fb[j] - (float)h1);
            }
        }
    }

    // aw2: A[row][k] = 1 at k=0,1 (w2-injection MFMA operand; per-lane constant)
    half8 aw2;
    #pragma unroll
    for (int j = 0; j < 8; ++j) aw2[j] = (lhalf == 0 && j < 2) ? (_Float16)1.0f : (_Float16)0.0f;

    // wave-private staging: instr p (0..7) stages granule G = p*64 + lane of the tile
    // content: code = cbase+ln31, halves offset = (p&1)*64 + lhalf*8 + (p>>1)*16
    const _Float16* srcb = wm2hl + (size_t)(cbase + ln31) * 128 + lhalf * 8;
    _Float16* slot0 = &lds[wv][0][0];
    _Float16* slot1 = &lds[wv][1][0];

    float bv0[16], bv1[16];
    int   bi0[16], bi1[16];
    #pragma unroll
    for (int s2 = 0; s2 < 16; ++s2) { bv0[s2] = 3.4e38f; bv1[s2] = 3.4e38f; bi0[s2] = 0; bi1[s2] = 0; }

    __syncthreads();   // w2lds ready; drains all prologue loads (vmcnt clean)

#define STAGE(tt, sl)                                                            \
    { _Pragma("unroll")                                                          \
      for (int p = 0; p < 8; ++p)                                                \
          gload_lds16(srcb + (size_t)(tt) * 4096 + (p & 1) * 64 + (p >> 1) * 16, \
                      (sl) + p * 512); }

    // prologue: 16 loads in flight (tiles 0 and 1)
    STAGE(0, slot0)
    STAGE(1, slot1)

#define TILE_BODY(VM, DO_STAGE, tt)                                              \
  {                                                                              \
    asm volatile("s_waitcnt vmcnt(" #VM ")" ::: "memory");                       \
    _Float16* sb = ((tt) & 1) ? slot1 : slot0;                                   \
    const _Float16* lb = sb;                                                     \
    unsigned pk = w2lds[(tt) * 32 + ln31];                                       \
    unsigned v0 = (lhalf == 0) ? pk : 0u;                                        \
    union { half8 h8; unsigned u[4]; } bw2u;                                     \
    bw2u.u[0] = v0; bw2u.u[1] = 0; bw2u.u[2] = 0; bw2u.u[3] = 0;                 \
    f32x16 acc0 = {}, acc1 = {};                                                 \
    __builtin_amdgcn_s_setprio(1);                                               \
    acc0 = __builtin_amdgcn_mfma_f32_32x32x16_f16(aw2, bw2u.h8, acc0, 0, 0, 0);  \
    acc1 = __builtin_amdgcn_mfma_f32_32x32x16_f16(aw2, bw2u.h8, acc1, 0, 0, 0);  \
    _Pragma("unroll")                                                            \
    for (int kt = 0; kt < 4; ++kt) {                                             \
      half8 bh = *(const half8*)(lb + ((kt * 2 + 0) * 64 + l) * 8);              \
      half8 bl = *(const half8*)(lb + ((kt * 2 + 1) * 64 + l) * 8);              \
      acc0 = __builtin_amdgcn_mfma_f32_32x32x16_f16(ahi0[kt], bh, acc0, 0, 0, 0);\
      acc1 = __builtin_amdgcn_mfma_f32_32x32x16_f16(ahi1[kt], bh, acc1, 0, 0, 0);\
      acc0 = __builtin_amdgcn_mfma_f32_32x32x16_f16(alo0[kt], bh, acc0, 0, 0, 0);\
      acc1 = __builtin_amdgcn_mfma_f32_32x32x16_f16(alo1[kt], bh, acc1, 0, 0, 0);\
      acc0 = __builtin_amdgcn_mfma_f32_32x32x16_f16(ahi0[kt], bl, acc0, 0, 0, 0);\
      acc1 = __builtin_amdgcn_mfma_f32_32x32x16_f16(alo1[kt], bl, acc1, 0, 0, 0);\
      acc1 = __builtin_amdgcn_mfma_f32_32x32x16_f16(ahi1[kt], bl, acc1, 0, 0, 0);\
      acc0 = __builtin_amdgcn_mfma_f32_32x32x16_f16(alo0[kt], bl, acc0, 0, 0, 0);\
    }                                                                            \
    __builtin_amdgcn_s_setprio(0);                                               \
    __builtin_amdgcn_sched_barrier(0);                                           \
    if (DO_STAGE) { STAGE((tt) + 2, sb) }                                        \
    const int cc = cbase + (tt) * 32 + ln31;                                     \
    _Pragma("unroll")                                                            \
    for (int s2 = 0; s2 < 16; ++s2) {                                            \
      float sA = acc0[s2];                                                       \
      float sB = acc1[s2];                                                       \
      if (sA < bv0[s2]) { bv0[s2] = sA; bi0[s2] = cc; }                          \
      if (sB < bv1[s2]) { bv1[s2] = sB; bi1[s2] = cc; }                          \
    }                                                                            \
  }

    for (int tile = 0; tile < TILES - 1; ++tile)
        TILE_BODY(8, (tile + 2 < TILES), tile);
    TILE_BODY(0, false, TILES - 1);
#undef TILE_BODY
#undef STAGE

    // per-row reduce across the 32 lanes sharing each row, then global merge
    #pragma unroll
    for (int rg = 0; rg < 2; ++rg) {
        #pragma unroll
        for (int s2 = 0; s2 < 16; ++s2) {
            float fv = rg ? bv1[s2] : bv0[s2];
            int   iv = rg ? bi1[s2] : bi0[s2];
            unsigned uk = __float_as_uint(fv);
            uk = (uk >> 31) ? ~uk : (uk | 0x80000000u);   // monotone float->uint
            unsigned long long key = ((unsigned long long)uk << 32) | (unsigned)iv;
            #pragma unroll
            for (int off = 16; off; off >>= 1) {
                unsigned long long o = __shfl_xor(key, off);
                key = (o < key) ? o : key;
            }
            if (ln31 == 0) {
                int rl = (s2 & 3) + 8 * (s2 >> 2) + 4 * lhalf;   // C/D row map (m74/m101)
                atomicMin(&best[rowb + rg * 32 + rl], key);
            }
        }
    }
}

// ---------------- kernel 3: gather z + histogram + commitment (identity) ----------------
__global__ __launch_bounds__(256) void vq_gather(const float* __restrict__ W,
                                                 const unsigned long long* __restrict__ best,
                                                 const float* __restrict__ x2g,
                                                 float* __restrict__ zout,
                                                 int* __restrict__ counts,
                                                 float* __restrict__ csum) {
    int t   = threadIdx.x;
    int row = blockIdx.x * 64 + (t >> 2);
    int seg = t & 3;
    unsigned long long key = best[row];
    int idx = (int)(key & 0xFFFFFFFFULL);

    const float* wrow = W    + (size_t)idx * DIM + seg * 16;
    float*       zrow = zout + (size_t)row * DIM + seg * 16;
    #pragma unroll
    for (int j = 0; j < 16; j += 4) *(float4*)(zrow + j) = *(const float4*)(wrow + j);

    float local = 0.f;
    if (seg == 0) {
        atomicAdd(&counts[idx], 1);
        unsigned uk = (unsigned)(key >> 32);
        unsigned ob = (uk & 0x80000000u) ? (uk & 0x7FFFFFFFu) : ~uk;   // inverse monotone map
        local = x2g[row] + __uint_as_float(ob);                        // = |x-W[idx]|^2
    }
    #pragma unroll
    for (int off = 32; off; off >>= 1) local += __shfl_down(local, off);
    if ((t & 63) == 0) atomicAdd(csum, local);
}

// ---------------- kernel 4: finalize scalars ----------------
__global__ __launch_bounds__(256) void vq_final(const int* __restrict__ counts,
                                                const float* __restrict__ csum,
                                                float* __restrict__ out3) {
    __shared__ float sh[4];
    float e = 0.f;
    for (int i = threadIdx.x; i < K_CODES; i += 256) {
        float p = (float)counts[i] * (1.0f / N_ROWS);
        e += p * logf(p + 1e-10f);
    }
    #pragma unroll
    for (int off = 32; off; off >>= 1) e += __shfl_down(e, off);
    if ((threadIdx.x & 63) == 0) sh[threadIdx.x >> 6] = e;
    __syncthreads();
    if (threadIdx.x == 0) {
        float tot = sh[0] + sh[1] + sh[2] + sh[3];
        out3[0] = 0.f;
        out3[1] = csum[0] * (1.0f / ((float)N_ROWS * DIM));
        out3[2] = expf(-tot);
    }
}

extern "C" void kernel_launch(void* const* d_in, const int* in_sizes, int n_in,
                              void* d_out, int out_size, void* d_ws, size_t ws_size,
                              hipStream_t stream) {
    (void)in_sizes; (void)n_in; (void)out_size; (void)ws_size;
    const float* x = (const float*)d_in[0];
    const float* W = (const float*)d_in[1];
    float* zout = (float*)d_out;
    float* out3 = (float*)d_out + (size_t)N_ROWS * DIM;

    unsigned*           w2hl   = (unsigned*)((char*)d_ws + WS_W2HL);
    int*                counts = (int*)((char*)d_ws + WS_COUNTS);
    float*              csum   = (float*)((char*)d_ws + WS_CSUM);
    unsigned long long* best   = (unsigned long long*)((char*)d_ws + WS_BEST);
    float*              x2g    = (float*)((char*)d_ws + WS_X2);
    _Float16*           wm2hl  = (_Float16*)((char*)d_ws + WS_WM2);

    vq_prep  <<<K_CODES * DIM / 256,     256, 0, stream>>>(W, x, wm2hl, w2hl, x2g, best, counts, csum);
    vq_mfma  <<<(N_ROWS / 256) * CHUNKS, 256, 0, stream>>>(x, wm2hl, w2hl, best);
    vq_gather<<<N_ROWS / 64,             256, 0, stream>>>(W, best, x2g, zout, counts, csum);
    vq_final <<<1,                       256, 0, stream>>>(counts, csum, out3);
}

// Round 10
// 160.724 us; speedup vs baseline: 1.1691x; 1.1691x over previous
//
#include <hip/hip_runtime.h>
#include <math.h>

#define N_ROWS 32768
#define K_CODES 8192
#define DIM 64
#define CHUNKS 8
#define CPC (K_CODES / CHUNKS)   // 1024 codes per chunk
#define TILES (CPC / 32)         // 32 tiles of 32 codes
#define ITERS (TILES / 2)        // 16 iterations, 2 tiles each

using half8  = __attribute__((ext_vector_type(8))) _Float16;
using f32x16 = __attribute__((ext_vector_type(16))) float;

// ---------------- ws layout ----------------
#define WS_W2HL   0          // u32 w2hl[8192] (packed f16 hi/lo of w2)   32 KB
#define WS_COUNTS 32768      // int counts[8192]                          32 KB
#define WS_CSUM   65536      // float csum (+pad)                         16 B
#define WS_BEST   65552      // u64 best[32768]                           256 KB
#define WS_X2     327696     // float x2g[32768]                          128 KB
#define WS_WM2    458768     // _Float16 wm2hl[8192][128]  2 MB  (-2W: hi[64]|lo[64])

__device__ __forceinline__ void gload_lds16(const _Float16* g, _Float16* l) {
    __builtin_amdgcn_global_load_lds(
        (const __attribute__((address_space(1))) void*)g,
        (__attribute__((address_space(3))) void*)l, 16, 0, 0);
}

// ---------------- kernel 1: (-2W) split + w2 packed + x2 + init ----------------
__global__ __launch_bounds__(256) void vq_prep(const float* __restrict__ W,
                                               const float* __restrict__ x,
                                               _Float16* __restrict__ wm2hl,
                                               unsigned* __restrict__ w2hl,
                                               float* __restrict__ x2g,
                                               unsigned long long* __restrict__ best,
                                               int* __restrict__ counts,
                                               float* __restrict__ csum) {
    int g = blockIdx.x * 256 + threadIdx.x;   // 0 .. 524287
    int code = g >> 6, k = g & 63;
    float w = W[g];
    float wm2 = -2.0f * w;
    _Float16 h  = (_Float16)wm2;
    _Float16 lo = (_Float16)(wm2 - (float)h);
    wm2hl[(size_t)code * 128 + k]      = h;
    wm2hl[(size_t)code * 128 + 64 + k] = lo;
    float s = w * w;
    #pragma unroll
    for (int off = 32; off; off >>= 1) s += __shfl_down(s, off);
    if (k == 0) {
        _Float16 wh = (_Float16)s;
        _Float16 wl = (_Float16)(s - (float)wh);
        unsigned pk = (unsigned)(unsigned short)__builtin_bit_cast(unsigned short, wh)
                    | ((unsigned)(unsigned short)__builtin_bit_cast(unsigned short, wl) << 16);
        w2hl[code] = pk;
    }
    // x2: thread g owns x[4g..4g+3]; 16 lanes per row
    float4 xv = *(const float4*)(x + (size_t)g * 4);
    float ss = xv.x * xv.x + xv.y * xv.y + xv.z * xv.z + xv.w * xv.w;
    #pragma unroll
    for (int off = 8; off; off >>= 1) ss += __shfl_down(ss, off);
    if ((g & 15) == 0) x2g[g >> 4] = ss;
    if (g < N_ROWS)  best[g] = ~0ULL;
    if (g < K_CODES) counts[g] = 0;
    if (g == 0)      *csum = 0.f;
}

// ---------------- kernel 2: MFMA scores + per-row argmin ----------------
// R6 skeleton; 2 tiles per barrier (independent MFMA chains), w2 injected via
// MFMA, CHUNKS=8. Block-shared staging, one __syncthreads per 2 tiles.
__global__ __launch_bounds__(256, 4) void vq_mfma(const float* __restrict__ x,
                                                  const _Float16* __restrict__ wm2hl,
                                                  const unsigned* __restrict__ w2g,
                                                  unsigned long long* __restrict__ best) {
    __shared__ __align__(16) _Float16 lds[4][4096];  // 4 tile buffers, 8KB each
    __shared__ unsigned w2lds[CPC];                  // 4 KB

    const int t     = threadIdx.x;
    const int wv    = t >> 6;
    const int l     = t & 63;
    const int ln31  = l & 31;
    const int lhalf = l >> 5;
    const int chunk = blockIdx.x & (CHUNKS - 1);
    const int rblk  = blockIdx.x / CHUNKS;
    const int rowb  = rblk * 128 + wv * 32;    // wave owns 32 rows
    const int cbase = chunk * CPC;

    // stage w2 chunk into LDS (4 KB)
    for (int i = t; i < CPC; i += 256) w2lds[i] = w2g[cbase + i];

    // A fragments: exact f16 hi/lo split of this lane's row slice
    half8 ahi[4], alo[4];
    {
        const float* xr = x + (size_t)(rowb + ln31) * DIM + lhalf * 8;
        #pragma unroll
        for (int kt = 0; kt < 4; ++kt) {
            float4 a0 = *(const float4*)(xr + kt * 16);
            float4 a1 = *(const float4*)(xr + kt * 16 + 4);
            float fa[8] = {a0.x, a0.y, a0.z, a0.w, a1.x, a1.y, a1.z, a1.w};
            #pragma unroll
            for (int j = 0; j < 8; ++j) {
                _Float16 h = (_Float16)fa[j];
                ahi[kt][j] = h;
                alo[kt][j] = (_Float16)(fa[j] - (float)h);
            }
        }
    }

    // aw2: A[row][k] = 1 at k=0,1 (w2-injection operand)
    half8 aw2;
    #pragma unroll
    for (int j = 0; j < 8; ++j) aw2[j] = (lhalf == 0 && j < 2) ? (_Float16)1.0f : (_Float16)0.0f;

    // block-shared staging map (R6-proven): wave wv, instr p stages granule
    // G = p*256 + wv*64 + lane of a tile; LDS linear dest = G*16B.
    const _Float16* srcp[2];
    int ldsG[2];
    #pragma unroll
    for (int p = 0; p < 2; ++p) {
        int q = p * 4 + wv;
        srcp[p] = wm2hl + (size_t)(cbase + ln31) * 128 + ((q & 1) * 8 + lhalf + 2 * (q >> 1)) * 8;
        ldsG[p] = (p * 256 + wv * 64) * 8;   // wave-uniform base (halves)
    }

    float bv[16];
    int   bi[16];
    #pragma unroll
    for (int s2 = 0; s2 < 16; ++s2) { bv[s2] = 3.4e38f; bi[s2] = 0; }

#define STAGE(tt)                                                                \
    { _Pragma("unroll")                                                          \
      for (int p = 0; p < 2; ++p)                                                \
          gload_lds16(srcp[p] + (size_t)(tt) * 4096,                             \
                      &lds[(tt) & 3][0] + ldsG[p]); }

    // prologue: stage tiles 0,1
    STAGE(0)
    STAGE(1)
    __syncthreads();   // w2lds + staged tiles ready

    for (int it = 0; it < ITERS; ++it) {
        const int tA = 2 * it, tB = 2 * it + 1;
        if (it < ITERS - 1) { STAGE(tA + 2) STAGE(tB + 2) }

        const _Float16* lbA = &lds[tA & 3][0];
        const _Float16* lbB = &lds[tB & 3][0];

        // w2 operands for both tiles
        unsigned pkA = w2lds[tA * 32 + ln31];
        unsigned pkB = w2lds[tB * 32 + ln31];
        union { half8 h8; unsigned u[4]; } bwA, bwB;
        bwA.u[0] = (lhalf == 0) ? pkA : 0u; bwA.u[1] = 0; bwA.u[2] = 0; bwA.u[3] = 0;
        bwB.u[0] = (lhalf == 0) ? pkB : 0u; bwB.u[1] = 0; bwB.u[2] = 0; bwB.u[3] = 0;

        f32x16 acc0 = {}, acc1 = {};
        __builtin_amdgcn_s_setprio(1);
        acc0 = __builtin_amdgcn_mfma_f32_32x32x16_f16(aw2, bwA.h8, acc0, 0, 0, 0);
        acc1 = __builtin_amdgcn_mfma_f32_32x32x16_f16(aw2, bwB.h8, acc1, 0, 0, 0);
        #pragma unroll
        for (int kt = 0; kt < 4; ++kt) {
            half8 bhA = *(const half8*)(lbA + ((kt * 2 + 0) * 64 + l) * 8);
            half8 blA = *(const half8*)(lbA + ((kt * 2 + 1) * 64 + l) * 8);
            half8 bhB = *(const half8*)(lbB + ((kt * 2 + 0) * 64 + l) * 8);
            half8 blB = *(const half8*)(lbB + ((kt * 2 + 1) * 64 + l) * 8);
            acc0 = __builtin_amdgcn_mfma_f32_32x32x16_f16(ahi[kt], bhA, acc0, 0, 0, 0);
            acc1 = __builtin_amdgcn_mfma_f32_32x32x16_f16(ahi[kt], bhB, acc1, 0, 0, 0);
            acc0 = __builtin_amdgcn_mfma_f32_32x32x16_f16(alo[kt], bhA, acc0, 0, 0, 0);
            acc1 = __builtin_amdgcn_mfma_f32_32x32x16_f16(alo[kt], bhB, acc1, 0, 0, 0);
            acc0 = __builtin_amdgcn_mfma_f32_32x32x16_f16(ahi[kt], blA, acc0, 0, 0, 0);
            acc1 = __builtin_amdgcn_mfma_f32_32x32x16_f16(ahi[kt], blB, acc1, 0, 0, 0);
        }
        __builtin_amdgcn_s_setprio(0);

        const int ccA = cbase + tA * 32 + ln31;
        const int ccB = cbase + tB * 32 + ln31;
        #pragma unroll
        for (int s2 = 0; s2 < 16; ++s2) {
            float sA = acc0[s2];
            float sB = acc1[s2];
            if (sA < bv[s2]) { bv[s2] = sA; bi[s2] = ccA; }
            if (sB < bv[s2]) { bv[s2] = sB; bi[s2] = ccB; }
        }
        __syncthreads();   // reads of current pair done; staged pair drained
    }
#undef STAGE

    // per-row reduce across the 32 lanes sharing each row, then global merge
    #pragma unroll
    for (int s2 = 0; s2 < 16; ++s2) {
        unsigned uk = __float_as_uint(bv[s2]);
        uk = (uk >> 31) ? ~uk : (uk | 0x80000000u);   // monotone float->uint
        unsigned long long key = ((unsigned long long)uk << 32) | (unsigned)bi[s2];
        #pragma unroll
        for (int off = 16; off; off >>= 1) {
            unsigned long long o = __shfl_xor(key, off);
            key = (o < key) ? o : key;
        }
        if (ln31 == 0) {
            int rl = (s2 & 3) + 8 * (s2 >> 2) + 4 * lhalf;   // C/D row map (m74/m101)
            atomicMin(&best[rowb + rl], key);
        }
    }
}

// ---------------- kernel 3: gather z + histogram + commitment (identity) ----------------
__global__ __launch_bounds__(256) void vq_gather(const float* __restrict__ W,
                                                 const unsigned long long* __restrict__ best,
                                                 const float* __restrict__ x2g,
                                                 float* __restrict__ zout,
                                                 int* __restrict__ counts,
                                                 float* __restrict__ csum) {
    int t   = threadIdx.x;
    int row = blockIdx.x * 64 + (t >> 2);
    int seg = t & 3;
    unsigned long long key = best[row];
    int idx = (int)(key & 0xFFFFFFFFULL);

    const float* wrow = W    + (size_t)idx * DIM + seg * 16;
    float*       zrow = zout + (size_t)row * DIM + seg * 16;
    #pragma unroll
    for (int j = 0; j < 16; j += 4) *(float4*)(zrow + j) = *(const float4*)(wrow + j);

    float local = 0.f;
    if (seg == 0) {
        atomicAdd(&counts[idx], 1);
        unsigned uk = (unsigned)(key >> 32);
        unsigned ob = (uk & 0x80000000u) ? (uk & 0x7FFFFFFFu) : ~uk;   // inverse monotone map
        local = x2g[row] + __uint_as_float(ob);                        // = |x-W[idx]|^2
    }
    #pragma unroll
    for (int off = 32; off; off >>= 1) local += __shfl_down(local, off);
    if ((t & 63) == 0) atomicAdd(csum, local);
}

// ---------------- kernel 4: finalize scalars ----------------
__global__ __launch_bounds__(256) void vq_final(const int* __restrict__ counts,
                                                const float* __restrict__ csum,
                                                float* __restrict__ out3) {
    __shared__ float sh[4];
    float e = 0.f;
    for (int i = threadIdx.x; i < K_CODES; i += 256) {
        float p = (float)counts[i] * (1.0f / N_ROWS);
        e += p * logf(p + 1e-10f);
    }
    #pragma unroll
    for (int off = 32; off; off >>= 1) e += __shfl_down(e, off);
    if ((threadIdx.x & 63) == 0) sh[threadIdx.x >> 6] = e;
    __syncthreads();
    if (threadIdx.x == 0) {
        float tot = sh[0] + sh[1] + sh[2] + sh[3];
        out3[0] = 0.f;
        out3[1] = csum[0] * (1.0f / ((float)N_ROWS * DIM));
        out3[2] = expf(-tot);
    }
}

extern "C" void kernel_launch(void* const* d_in, const int* in_sizes, int n_in,
                              void* d_out, int out_size, void* d_ws, size_t ws_size,
                              hipStream_t stream) {
    (void)in_sizes; (void)n_in; (void)out_size; (void)ws_size;
    const float* x = (const float*)d_in[0];
    const float* W = (const float*)d_in[1];
    float* zout = (float*)d_out;
    float* out3 = (float*)d_out + (size_t)N_ROWS * DIM;

    unsigned*           w2hl   = (unsigned*)((char*)d_ws + WS_W2HL);
    int*                counts = (int*)((char*)d_ws + WS_COUNTS);
    float*              csum   = (float*)((char*)d_ws + WS_CSUM);
    unsigned long long* best   = (unsigned long long*)((char*)d_ws + WS_BEST);
    float*              x2g    = (float*)((char*)d_ws + WS_X2);
    _Float16*           wm2hl  = (_Float16*)((char*)d_ws + WS_WM2);

    vq_prep  <<<K_CODES * DIM / 256,     256, 0, stream>>>(W, x, wm2hl, w2hl, x2g, best, counts, csum);
    vq_mfma  <<<(N_ROWS / 128) * CHUNKS, 256, 0, stream>>>(x, wm2hl, w2hl, best);
    vq_gather<<<N_ROWS / 64,             256, 0, stream>>>(W, best, x2g, zout, counts, csum);
    vq_final <<<1,                       256, 0, stream>>>(counts, csum, out3);
}

// Round 11
// 151.979 us; speedup vs baseline: 1.2364x; 1.0575x over previous
//
#include <hip/hip_runtime.h>
#include <math.h>

#define N_ROWS 32768
#define K_CODES 8192
#define DIM 64
#define CHUNKS 4
#define CPC (K_CODES / CHUNKS)   // 2048 codes per chunk
#define TILES (CPC / 32)         // 64 tiles of 32 codes

using half8  = __attribute__((ext_vector_type(8))) _Float16;
using f32x16 = __attribute__((ext_vector_type(16))) float;

// ---------------- ws layout ----------------
#define WS_W2     0          // float w2g[8192]            32 KB
#define WS_COUNTS 32768      // int counts[8192]           32 KB
#define WS_CSUM   65536      // float csum                 4 B
#define WS_ESUM   65540      // float esum                 4 B
#define WS_DONE   65544      // int done                   4 B (+pad)
#define WS_BEST   65552      // u64 best[32768]            256 KB
#define WS_X2     327696     // float x2g[32768]           128 KB
#define WS_WHL    458768     // _Float16 whl[8192][128]    2 MB (hi[64]|lo[64])

__device__ __forceinline__ void gload_lds16(const _Float16* g, _Float16* l) {
    __builtin_amdgcn_global_load_lds(
        (const __attribute__((address_space(1))) void*)g,
        (__attribute__((address_space(3))) void*)l, 16, 0, 0);
}

// ---------------- kernel 1: W hi/lo split + w2 + x2 + init ----------------
__global__ __launch_bounds__(256) void vq_prep(const float* __restrict__ W,
                                               const float* __restrict__ x,
                                               _Float16* __restrict__ whl,
                                               float* __restrict__ w2g,
                                               float* __restrict__ x2g,
                                               unsigned long long* __restrict__ best,
                                               int* __restrict__ counts,
                                               float* __restrict__ scal,
                                               int* __restrict__ done) {
    int g = blockIdx.x * 256 + threadIdx.x;   // 0 .. 524287
    int code = g >> 6, k = g & 63;
    float w = W[g];
    _Float16 h  = (_Float16)w;
    _Float16 lo = (_Float16)(w - (float)h);
    whl[(size_t)code * 128 + k]      = h;
    whl[(size_t)code * 128 + 64 + k] = lo;
    float s = w * w;
    #pragma unroll
    for (int off = 32; off; off >>= 1) s += __shfl_down(s, off);
    if (k == 0) w2g[code] = s;
    // x2: thread g owns x[4g..4g+3]; 16 lanes per row
    float4 xv = *(const float4*)(x + (size_t)g * 4);
    float ss = xv.x * xv.x + xv.y * xv.y + xv.z * xv.z + xv.w * xv.w;
    #pragma unroll
    for (int off = 8; off; off >>= 1) ss += __shfl_down(ss, off);
    if ((g & 15) == 0) x2g[g >> 4] = ss;
    if (g < N_ROWS)  best[g] = ~0ULL;
    if (g < K_CODES) counts[g] = 0;
    if (g == 0) { scal[0] = 0.f; scal[1] = 0.f; *done = 0; }   // csum, esum, ticket
}

// ---------------- kernel 2: MFMA scores + per-row argmin ----------------
// R6 body; 4-slot LDS ring with counted vmcnt(4) + raw s_barrier (T3-min + T4).
// Steady state: 3 tiles / 6 loads in flight, never drained to 0 until epilogue.
__global__ __launch_bounds__(256, 4) void vq_mfma(const float* __restrict__ x,
                                                  const _Float16* __restrict__ whl,
                                                  const float* __restrict__ w2g,
                                                  unsigned long long* __restrict__ best) {
    __shared__ __align__(16) _Float16 ring[4][4096];  // 32 KB (4 tile slots)
    __shared__ float w2l[CPC];                        // 8 KB -> 40960 B total

    const int t     = threadIdx.x;
    const int wv    = t >> 6;
    const int l     = t & 63;
    const int ln31  = l & 31;
    const int lhalf = l >> 5;
    const int chunk = blockIdx.x & (CHUNKS - 1);
    const int rblk  = blockIdx.x / CHUNKS;
    const int rowb  = rblk * 128 + wv * 32;    // wave owns 32 rows
    const int cbase = chunk * CPC;

    // stage w2 chunk into LDS (keeps the K-loop's vmcnt stream = staging only)
    for (int i = t; i < CPC; i += 256) w2l[i] = w2g[cbase + i];

    // A fragments: exact f16 hi/lo split of this lane's row slice
    half8 ahi[4], alo[4];
    {
        const float* xr = x + (size_t)(rowb + ln31) * DIM + lhalf * 8;
        #pragma unroll
        for (int kt = 0; kt < 4; ++kt) {
            float4 a0 = *(const float4*)(xr + kt * 16);
            float4 a1 = *(const float4*)(xr + kt * 16 + 4);
            float fa[8] = {a0.x, a0.y, a0.z, a0.w, a1.x, a1.y, a1.z, a1.w};
            #pragma unroll
            for (int j = 0; j < 8; ++j) {
                _Float16 h = (_Float16)fa[j];
                ahi[kt][j] = h;
                alo[kt][j] = (_Float16)(fa[j] - (float)h);
            }
        }
    }

    // staging map (R6-proven): wave wv, instr p stages granule G = p*256+wv*64+lane
    const _Float16* srcp[2];
    int ldsG[2];
    #pragma unroll
    for (int p = 0; p < 2; ++p) {
        int q = p * 4 + wv;
        srcp[p] = whl + (size_t)(cbase + ln31) * 128 + ((q & 1) * 8 + lhalf + 2 * (q >> 1)) * 8;
        ldsG[p] = (p * 256 + wv * 64) * 8;   // wave-uniform base (halves)
    }

    float bv[16];
    int   bi[16];
    #pragma unroll
    for (int s2 = 0; s2 < 16; ++s2) { bv[s2] = 3.4e38f; bi[s2] = 0; }

#define STAGE(tt)                                                                \
    { _Pragma("unroll")                                                          \
      for (int p = 0; p < 2; ++p)                                                \
          gload_lds16(srcp[p] + (size_t)(tt) * 4096,                             \
                      &ring[(tt) & 3][0] + ldsG[p]); }

    // prologue: tiles 0,1,2 in flight (6 loads)
    STAGE(0) STAGE(1) STAGE(2)
    __syncthreads();   // w2l ready; vmcnt drained once here (prologue only)

#define TILE_BODY(VM, DO_STAGE, tt)                                              \
  {                                                                              \
    asm volatile("s_waitcnt vmcnt(" #VM ")" ::: "memory");                       \
    __builtin_amdgcn_s_barrier();                                                \
    if (DO_STAGE) { STAGE((tt) + 3) }  /* slot (tt-1)&3: readers passed barrier */\
    const _Float16* lb = &ring[(tt) & 3][0];                                     \
    const float w2v = w2l[(tt) * 32 + ln31];                                     \
    f32x16 acc = {};                                                             \
    __builtin_amdgcn_s_setprio(1);                                               \
    _Pragma("unroll")                                                            \
    for (int kt = 0; kt < 4; ++kt) {                                             \
      half8 bh = *(const half8*)(lb + ((kt * 2 + 0) * 64 + l) * 8);              \
      half8 bl = *(const half8*)(lb + ((kt * 2 + 1) * 64 + l) * 8);              \
      acc = __builtin_amdgcn_mfma_f32_32x32x16_f16(ahi[kt], bh, acc, 0, 0, 0);   \
      acc = __builtin_amdgcn_mfma_f32_32x32x16_f16(alo[kt], bh, acc, 0, 0, 0);   \
      acc = __builtin_amdgcn_mfma_f32_32x32x16_f16(ahi[kt], bl, acc, 0, 0, 0);   \
    }                                                                            \
    __builtin_amdgcn_s_setprio(0);                                               \
    const int cc = cbase + (tt) * 32 + ln31;                                     \
    _Pragma("unroll")                                                            \
    for (int s2 = 0; s2 < 16; ++s2) {                                            \
      float sA = fmaf(-2.f, acc[s2], w2v);                                       \
      if (sA < bv[s2]) { bv[s2] = sA; bi[s2] = cc; }                             \
    }                                                                            \
  }

    for (int tile = 0; tile < TILES - 3; ++tile)
        TILE_BODY(4, true, tile);          // steady state: never drain to 0
    TILE_BODY(4, false, TILES - 3);
    TILE_BODY(2, false, TILES - 2);
    TILE_BODY(0, false, TILES - 1);
#undef TILE_BODY
#undef STAGE

    // per-row reduce across the 32 lanes sharing each row, then global merge
    #pragma unroll
    for (int s2 = 0; s2 < 16; ++s2) {
        unsigned uk = __float_as_uint(bv[s2]);
        uk = (uk >> 31) ? ~uk : (uk | 0x80000000u);   // monotone float->uint
        unsigned long long key = ((unsigned long long)uk << 32) | (unsigned)bi[s2];
        #pragma unroll
        for (int off = 16; off; off >>= 1) {
            unsigned long long o = __shfl_xor(key, off);
            key = (o < key) ? o : key;
        }
        if (ln31 == 0) {
            int rl = (s2 & 3) + 8 * (s2 >> 2) + 4 * lhalf;   // C/D row map (m74/m101)
            atomicMin(&best[rowb + rl], key);
        }
    }
}

// ---------------- kernel 3: gather z + histogram + commitment (identity) ----------------
__global__ __launch_bounds__(256) void vq_gather(const float* __restrict__ W,
                                                 const unsigned long long* __restrict__ best,
                                                 const float* __restrict__ x2g,
                                                 float* __restrict__ zout,
                                                 int* __restrict__ counts,
                                                 float* __restrict__ csum) {
    int t   = threadIdx.x;
    int row = blockIdx.x * 64 + (t >> 2);
    int seg = t & 3;
    unsigned long long key = best[row];
    int idx = (int)(key & 0xFFFFFFFFULL);

    const float* wrow = W    + (size_t)idx * DIM + seg * 16;
    float*       zrow = zout + (size_t)row * DIM + seg * 16;
    #pragma unroll
    for (int j = 0; j < 16; j += 4) *(float4*)(zrow + j) = *(const float4*)(wrow + j);

    float local = 0.f;
    if (seg == 0) {
        atomicAdd(&counts[idx], 1);
        unsigned uk = (unsigned)(key >> 32);
        unsigned ob = (uk & 0x80000000u) ? (uk & 0x7FFFFFFFu) : ~uk;   // inverse monotone map
        local = x2g[row] + __uint_as_float(ob);                        // = |x-W[idx]|^2
    }
    #pragma unroll
    for (int off = 32; off; off >>= 1) local += __shfl_down(local, off);
    if ((t & 63) == 0) atomicAdd(csum, local);
}

// ---------------- kernel 4: entropy (32 blocks) + last-block finalize ----------------
__global__ __launch_bounds__(256) void vq_final(const int* __restrict__ counts,
                                                float* __restrict__ scal,   // [csum, esum]
                                                int* __restrict__ done,
                                                float* __restrict__ out3) {
    __shared__ float sh[4];
    int g = blockIdx.x * 256 + threadIdx.x;   // 8192 threads total
    float p = (float)counts[g] * (1.0f / N_ROWS);
    float e = p * logf(p + 1e-10f);
    #pragma unroll
    for (int off = 32; off; off >>= 1) e += __shfl_down(e, off);
    if ((threadIdx.x & 63) == 0) sh[threadIdx.x >> 6] = e;
    __syncthreads();
    if (threadIdx.x == 0) {
        atomicAdd(&scal[1], sh[0] + sh[1] + sh[2] + sh[3]);
        __threadfence();
        int old = atomicAdd(done, 1);
        if (old == 31) {   // last block: all 32 esum contributions visible
            float es = atomicAdd(&scal[1], 0.f);
            float cs = atomicAdd(&scal[0], 0.f);
            out3[0] = 0.f;
            out3[1] = cs * (1.0f / ((float)N_ROWS * DIM));
            out3[2] = expf(-es);
        }
    }
}

extern "C" void kernel_launch(void* const* d_in, const int* in_sizes, int n_in,
                              void* d_out, int out_size, void* d_ws, size_t ws_size,
                              hipStream_t stream) {
    (void)in_sizes; (void)n_in; (void)out_size; (void)ws_size;
    const float* x = (const float*)d_in[0];
    const float* W = (const float*)d_in[1];
    float* zout = (float*)d_out;
    float* out3 = (float*)d_out + (size_t)N_ROWS * DIM;

    float*              w2g    = (float*)((char*)d_ws + WS_W2);
    int*                counts = (int*)((char*)d_ws + WS_COUNTS);
    float*              scal   = (float*)((char*)d_ws + WS_CSUM);   // [csum, esum]
    int*                done   = (int*)((char*)d_ws + WS_DONE);
    unsigned long long* best   = (unsigned long long*)((char*)d_ws + WS_BEST);
    float*              x2g    = (float*)((char*)d_ws + WS_X2);
    _Float16*           whl    = (_Float16*)((char*)d_ws + WS_WHL);

    vq_prep  <<<K_CODES * DIM / 256,     256, 0, stream>>>(W, x, whl, w2g, x2g, best, counts, scal, done);
    vq_mfma  <<<(N_ROWS / 128) * CHUNKS, 256, 0, stream>>>(x, whl, w2g, best);
    vq_gather<<<N_ROWS / 64,             256, 0, stream>>>(W, best, x2g, zout, counts, &scal[0]);
    vq_final <<<K_CODES / 256,           256, 0, stream>>>(counts, scal, done, out3);
}